// Round 12
// baseline (65.379 us; speedup 1.0000x reference)
//
#include <hip/hip_runtime.h>
#include <hip/hip_bf16.h>
#include <stdint.h>

#define NROWS 8192
#define BROWS 4096
#define LN2 0.6931471805599453f
#define FSC 8.944507e-4f        // (1/T)*log2(e) / 127^2, T=0.1
#define NBLK 528                // sum_{it=0}^{31} (32-it) = 8*66

typedef __attribute__((ext_vector_type(4))) int i32x4;

__device__ inline void gload_lds16(const void* g, void* l) {
  __builtin_amdgcn_global_load_lds((const __attribute__((address_space(1))) void*)g,
                                   (__attribute__((address_space(3))) void*)l,
                                   16, 0, 0);
}

// Kernel A: L2-normalize rows, quantize to i8 (q = rn(127*v/||v||)); zero denom/out.
__global__ __launch_bounds__(256) void knorm(const float* __restrict__ zi,
                                             const float* __restrict__ zj,
                                             int* __restrict__ reps,   // i8 packed, 64 ints/row
                                             float* __restrict__ denom,
                                             float* __restrict__ out) {
  int w = threadIdx.x >> 6, l = threadIdx.x & 63;
  int row = blockIdx.x * 4 + w;
  const float* src = (row < BROWS) ? (zi + (size_t)row * 256)
                                   : (zj + (size_t)(row - BROWS) * 256);
  float4 v = ((const float4*)src)[l];
  float ss = v.x * v.x + v.y * v.y + v.z * v.z + v.w * v.w;
#pragma unroll
  for (int m = 1; m < 64; m <<= 1) ss += __shfl_xor(ss, m, 64);
  float sc = 127.0f / fmaxf(sqrtf(ss), 1e-12f);
  int q0 = __float2int_rn(v.x * sc), q1 = __float2int_rn(v.y * sc);
  int q2 = __float2int_rn(v.z * sc), q3 = __float2int_rn(v.w * sc);
  reps[(size_t)row * 64 + l] =
      (q0 & 255) | ((q1 & 255) << 8) | ((q2 & 255) << 16) | ((q3 & 255) << 24);
  if (l == 0) denom[row] = 0.f;
  if (row == 0 && l == 0) out[0] = 0.f;
}

// Kernel B: upper-tri sim, i8 MFMA 16x16x64. 256-row strips (8 waves x 32 rows,
// 512 threads) x 256-col chunks -> 528 blocks, 4 tiles of 64 cols each.
// Per-wave core identical to R11; phases and staged bytes both halved.
__global__ __launch_bounds__(512, 4) void ksim(const int* __restrict__ reps_,
                                               float* __restrict__ denom,
                                               float* __restrict__ pos) {
  __shared__ uint4 smem[2][1024];    // 2 x 64 reps-rows x 256 B = 32 KB
  __shared__ float colacc[256];      // 1 KB
  int tid = threadIdx.x, w = tid >> 6, l = tid & 63;
  int kgrp = l >> 4;

  // ---- XCD swizzle (528 = 8*66, bijective) + block -> (strip it, chunk q) ----
  int b = blockIdx.x;
  int orig = (b & 7) * 66 + (b >> 3);
  int rem = orig, it = 0, ch;
  while (rem >= (ch = 32 - it)) { rem -= ch; ++it; }
  int q = rem;
  int rowbase = it * 256;
  int cs0 = rowbase + q * 256;       // chunk is always full 256 cols (exact partition)

  if (tid < 256) colacc[tid] = 0.f;

  // ---- staging: 64 reps-rows x 256B -> 16KB buffer; linear dest, swizzled src.
  //      16 chunks of 1KB (4 rows each); 8 waves x 2 chunks ----
  auto stage = [&](int bufi, int colbase) {
#pragma unroll
    for (int i = 0; i < 2; ++i) {
      int c2 = w * 2 + i;
      int lr = c2 * 4 + (l >> 4);    // local row 0..63
      int kb = ((l & 15) * 16) ^ ((lr & 3) << 4);
      gload_lds16((const char*)reps_ + (size_t)(colbase + lr) * 256 + kb,
                  (void*)&smem[bufi][c2 * 64]);
    }
  };
  stage(0, cs0);

  // ---- A fragments: wave w owns rows rowbase+32w..+32; lane holds row
  //      +fr*16+(l&15), bytes [kk*64 + kgrp*16, +16) ----
  i32x4 a[2][4];
  {
    const uint4* r4 = (const uint4*)reps_;
    int arow = rowbase + w * 32 + (l & 15);
#pragma unroll
    for (int fr = 0; fr < 2; ++fr)
#pragma unroll
      for (int kk = 0; kk < 4; ++kk)
        a[fr][kk] = __builtin_bit_cast(i32x4,
            r4[(size_t)(arow + fr * 16) * 16 + kk * 4 + kgrp]);
  }

  // ---- per-kk LDS byte offsets for fc=0 (row = l&15); fc adds +16*256 ----
  int lds_a[4];
  {
    int r0l = l & 15;
    int swz = (r0l & 3) << 4;
#pragma unroll
    for (int kk = 0; kk < 4; ++kk)
      lds_a[kk] = r0l * 256 + ((kk * 64 + kgrp * 16) ^ swz);
  }

  float rowsum[2][4];
#pragma unroll
  for (int fr = 0; fr < 2; ++fr)
#pragma unroll
    for (int r = 0; r < 4; ++r) rowsum[fr][r] = 0.f;

  int r0 = rowbase + w * 32 + kgrp * 4;
  int buf = 0;
  bool docol = (q != 0);             // q==0 chunk is the symmetric diag block
  bool posChunk = (q == 16);         // holds cols rowbase+4096..+256 for it<16

#pragma unroll
  for (int t = 0; t < 4; ++t) {
    asm volatile("s_waitcnt vmcnt(0)" ::: "memory");   // own stage(t) loads landed
    __builtin_amdgcn_sched_barrier(0);
    __builtin_amdgcn_s_barrier();      // all waves' stage(t) landed; buf^1 free
    __builtin_amdgcn_sched_barrier(0);
    if (t < 3) stage(buf ^ 1, cs0 + 64 * (t + 1));

    const char* bb = (const char*)&smem[0][0] + buf * 16384;
    i32x4 acc[2][4];
    const i32x4 zero = {0, 0, 0, 0};
    __builtin_amdgcn_s_setprio(1);
#pragma unroll
    for (int kk = 0; kk < 4; ++kk) {
      i32x4 bf[4];
#pragma unroll
      for (int fc = 0; fc < 4; ++fc)
        bf[fc] = *(const i32x4*)(bb + lds_a[kk] + fc * 4096);
#pragma unroll
      for (int fr = 0; fr < 2; ++fr)
#pragma unroll
        for (int fc = 0; fc < 4; ++fc) {
          if (kk == 0)
            acc[fr][fc] = __builtin_amdgcn_mfma_i32_16x16x64_i8(a[fr][0], bf[fc], zero, 0, 0, 0);
          else
            acc[fr][fc] = __builtin_amdgcn_mfma_i32_16x16x64_i8(a[fr][kk], bf[fc], acc[fr][fc], 0, 0, 0);
        }
    }
    __builtin_amdgcn_s_setprio(0);

    // ---- epilogue: s = I*FSC; e = exp2(s); diag mask; rowsum + col partials ----
    int cb = cs0 + 64 * t;
    float cp[4] = {0.f, 0.f, 0.f, 0.f};
    int cbase = cb + (l & 15);
#pragma unroll
    for (int fr = 0; fr < 2; ++fr)
#pragma unroll
      for (int fc = 0; fc < 4; ++fc)
#pragma unroll
        for (int r = 0; r < 4; ++r) {
          int rg = r0 + fr * 16 + r;
          int cg = cbase + fc * 16;
          float s = (float)acc[fr][fc][r] * FSC;
          float e = __builtin_amdgcn_exp2f(s);
          e = (rg == cg) ? 0.f : e;
          if (posChunk && cg == rg + BROWS) pos[rg] = s;
          rowsum[fr][r] += e;
          cp[fc] += e;
        }
    if (docol) {
#pragma unroll
      for (int fc = 0; fc < 4; ++fc) {
        cp[fc] += __shfl_xor(cp[fc], 16, 64);
        cp[fc] += __shfl_xor(cp[fc], 32, 64);
      }
      if (l < 16) {
        int off = (cb - cs0) + l;
#pragma unroll
        for (int fc = 0; fc < 4; ++fc)
          atomicAdd(&colacc[off + fc * 16], cp[fc]);
      }
    }
    buf ^= 1;
  }

  // ---- row sums: reduce 16 col-lanes; 4 lanes atomic per wave ----
#pragma unroll
  for (int fr = 0; fr < 2; ++fr)
#pragma unroll
    for (int r = 0; r < 4; ++r) {
      float v = rowsum[fr][r];
      v += __shfl_xor(v, 1, 64);
      v += __shfl_xor(v, 2, 64);
      v += __shfl_xor(v, 4, 64);
      v += __shfl_xor(v, 8, 64);
      if ((l & 15) == 0) atomicAdd(&denom[r0 + fr * 16 + r], v);
    }

  // ---- col sums: flush colacc, one atomic per column ----
  __syncthreads();
  if (docol && tid < 256) {
    float v = colacc[tid];
    if (v != 0.f) atomicAdd(&denom[cs0 + tid], v);
  }
}

// Kernel F: + (1/N) * sum_i (log(denom_i) - pos_{i mod B} * ln2)   [pos in log2 units]
__global__ __launch_bounds__(256) void kfin(const float* __restrict__ denom,
                                            const float* __restrict__ pos,
                                            float* __restrict__ out) {
  int i = blockIdx.x * 256 + threadIdx.x;
  float v = (logf(denom[i]) - pos[i & 4095] * LN2) * (1.0f / 8192.0f);
#pragma unroll
  for (int m = 1; m < 64; m <<= 1) v += __shfl_xor(v, m, 64);
  __shared__ float part[4];
  if ((threadIdx.x & 63) == 0) part[threadIdx.x >> 6] = v;
  __syncthreads();
  if (threadIdx.x == 0)
    atomicAdd(out, part[0] + part[1] + part[2] + part[3]);
}

extern "C" void kernel_launch(void* const* d_in, const int* in_sizes, int n_in,
                              void* d_out, int out_size, void* d_ws, size_t ws_size,
                              hipStream_t stream) {
  (void)in_sizes; (void)n_in; (void)out_size; (void)ws_size;
  const float* zi = (const float*)d_in[0];
  const float* zj = (const float*)d_in[1];
  float* out = (float*)d_out;
  char* ws = (char*)d_ws;
  int* reps    = (int*)ws;                                    // 2 MB (i8 packed)
  float* denom = (float*)(ws + 2097152);                      // 32 KB
  float* pos   = (float*)(ws + 2097152 + 32768);              // 16 KB

  knorm<<<2048, 256, 0, stream>>>(zi, zj, reps, denom, out);
  ksim<<<NBLK, 512, 0, stream>>>(reps, denom, pos);
  kfin<<<32, 256, 0, stream>>>(denom, pos, out);
}

// Round 13
// 58.566 us; speedup vs baseline: 1.1163x; 1.1163x over previous
//
#include <hip/hip_runtime.h>
#include <hip/hip_bf16.h>
#include <stdint.h>

#define NROWS 8192
#define BROWS 4096
#define LN2 0.6931471805599453f
#define FSC 8.944507e-4f        // (1/T)*log2(e) / 127^2, T=0.1
#define NBLK 528                // sum_{it=0}^{31} (32-it) = 8*66

typedef __attribute__((ext_vector_type(4))) int i32x4;

__device__ inline void gload_lds16(const void* g, void* l) {
  __builtin_amdgcn_global_load_lds((const __attribute__((address_space(1))) void*)g,
                                   (__attribute__((address_space(3))) void*)l,
                                   16, 0, 0);
}

// Kernel A: L2-normalize rows, quantize to i8 (q = rn(127*v/||v||)); zero denom/out.
__global__ __launch_bounds__(256) void knorm(const float* __restrict__ zi,
                                             const float* __restrict__ zj,
                                             int* __restrict__ reps,   // i8 packed, 64 ints/row
                                             float* __restrict__ denom,
                                             float* __restrict__ out) {
  int w = threadIdx.x >> 6, l = threadIdx.x & 63;
  int row = blockIdx.x * 4 + w;
  const float* src = (row < BROWS) ? (zi + (size_t)row * 256)
                                   : (zj + (size_t)(row - BROWS) * 256);
  float4 v = ((const float4*)src)[l];
  float ss = v.x * v.x + v.y * v.y + v.z * v.z + v.w * v.w;
#pragma unroll
  for (int m = 1; m < 64; m <<= 1) ss += __shfl_xor(ss, m, 64);
  float sc = 127.0f / fmaxf(sqrtf(ss), 1e-12f);
  int q0 = __float2int_rn(v.x * sc), q1 = __float2int_rn(v.y * sc);
  int q2 = __float2int_rn(v.z * sc), q3 = __float2int_rn(v.w * sc);
  reps[(size_t)row * 64 + l] =
      (q0 & 255) | ((q1 & 255) << 8) | ((q2 & 255) << 16) | ((q3 & 255) << 24);
  if (l == 0) denom[row] = 0.f;
  if (row == 0 && l == 0) out[0] = 0.f;
}

// Kernel B: upper-tri sim, i8 MFMA 16x16x64. 256-row strips (8 waves x 32 rows,
// 512 threads) x 256-col chunks -> 528 blocks, 4 tiles of 64 cols each.
// launch_bounds(512,2): 2 blocks/CU = 16 waves/CU, VGPR cap 128 (no spill).
__global__ __launch_bounds__(512, 2) void ksim(const int* __restrict__ reps_,
                                               float* __restrict__ denom,
                                               float* __restrict__ pos) {
  __shared__ uint4 smem[2][1024];    // 2 x 64 reps-rows x 256 B = 32 KB
  __shared__ float colacc[256];      // 1 KB
  int tid = threadIdx.x, w = tid >> 6, l = tid & 63;
  int kgrp = l >> 4;

  // ---- XCD swizzle (528 = 8*66, bijective) + block -> (strip it, chunk q) ----
  int b = blockIdx.x;
  int orig = (b & 7) * 66 + (b >> 3);
  int rem = orig, it = 0, ch;
  while (rem >= (ch = 32 - it)) { rem -= ch; ++it; }
  int q = rem;
  int rowbase = it * 256;
  int cs0 = rowbase + q * 256;       // chunk is always full 256 cols (exact partition)

  if (tid < 256) colacc[tid] = 0.f;

  // ---- staging: 64 reps-rows x 256B -> 16KB buffer; linear dest, swizzled src.
  //      16 chunks of 1KB (4 rows each); 8 waves x 2 chunks ----
  auto stage = [&](int bufi, int colbase) {
#pragma unroll
    for (int i = 0; i < 2; ++i) {
      int c2 = w * 2 + i;
      int lr = c2 * 4 + (l >> 4);    // local row 0..63
      int kb = ((l & 15) * 16) ^ ((lr & 3) << 4);
      gload_lds16((const char*)reps_ + (size_t)(colbase + lr) * 256 + kb,
                  (void*)&smem[bufi][c2 * 64]);
    }
  };
  stage(0, cs0);

  // ---- A fragments: wave w owns rows rowbase+32w..+32; lane holds row
  //      +fr*16+(l&15), bytes [kk*64 + kgrp*16, +16) ----
  i32x4 a[2][4];
  {
    const uint4* r4 = (const uint4*)reps_;
    int arow = rowbase + w * 32 + (l & 15);
#pragma unroll
    for (int fr = 0; fr < 2; ++fr)
#pragma unroll
      for (int kk = 0; kk < 4; ++kk)
        a[fr][kk] = __builtin_bit_cast(i32x4,
            r4[(size_t)(arow + fr * 16) * 16 + kk * 4 + kgrp]);
  }

  // ---- per-kk LDS byte offsets for fc=0 (row = l&15); fc adds +16*256 ----
  int lds_a[4];
  {
    int r0l = l & 15;
    int swz = (r0l & 3) << 4;
#pragma unroll
    for (int kk = 0; kk < 4; ++kk)
      lds_a[kk] = r0l * 256 + ((kk * 64 + kgrp * 16) ^ swz);
  }

  float rowsum[2][4];
#pragma unroll
  for (int fr = 0; fr < 2; ++fr)
#pragma unroll
    for (int r = 0; r < 4; ++r) rowsum[fr][r] = 0.f;

  int r0 = rowbase + w * 32 + kgrp * 4;
  int buf = 0;
  bool docol = (q != 0);             // q==0 chunk is the symmetric diag block
  bool posChunk = (q == 16);         // holds cols rowbase+4096..+256 (it<16)

#pragma unroll
  for (int t = 0; t < 4; ++t) {
    asm volatile("s_waitcnt vmcnt(0)" ::: "memory");   // own stage(t) loads landed
    __builtin_amdgcn_sched_barrier(0);
    __builtin_amdgcn_s_barrier();      // all waves' stage(t) landed; buf^1 free
    __builtin_amdgcn_sched_barrier(0);
    if (t < 3) stage(buf ^ 1, cs0 + 64 * (t + 1));

    const char* bb = (const char*)&smem[0][0] + buf * 16384;
    i32x4 acc[2][4];
    const i32x4 zero = {0, 0, 0, 0};
    __builtin_amdgcn_s_setprio(1);
#pragma unroll
    for (int kk = 0; kk < 4; ++kk) {
      i32x4 bf[4];
#pragma unroll
      for (int fc = 0; fc < 4; ++fc)
        bf[fc] = *(const i32x4*)(bb + lds_a[kk] + fc * 4096);
#pragma unroll
      for (int fr = 0; fr < 2; ++fr)
#pragma unroll
        for (int fc = 0; fc < 4; ++fc) {
          if (kk == 0)
            acc[fr][fc] = __builtin_amdgcn_mfma_i32_16x16x64_i8(a[fr][0], bf[fc], zero, 0, 0, 0);
          else
            acc[fr][fc] = __builtin_amdgcn_mfma_i32_16x16x64_i8(a[fr][kk], bf[fc], acc[fr][fc], 0, 0, 0);
        }
    }
    __builtin_amdgcn_s_setprio(0);

    // ---- epilogue: s = I*FSC; e = exp2(s); diag mask; rowsum + col partials ----
    int cb = cs0 + 64 * t;
    float cp[4] = {0.f, 0.f, 0.f, 0.f};
    int cbase = cb + (l & 15);
#pragma unroll
    for (int fr = 0; fr < 2; ++fr)
#pragma unroll
      for (int fc = 0; fc < 4; ++fc)
#pragma unroll
        for (int r = 0; r < 4; ++r) {
          int rg = r0 + fr * 16 + r;
          int cg = cbase + fc * 16;
          float s = (float)acc[fr][fc][r] * FSC;
          float e = __builtin_amdgcn_exp2f(s);
          e = (rg == cg) ? 0.f : e;
          if (posChunk && cg == rg + BROWS) pos[rg] = s;
          rowsum[fr][r] += e;
          cp[fc] += e;
        }
    if (docol) {
#pragma unroll
      for (int fc = 0; fc < 4; ++fc) {
        cp[fc] += __shfl_xor(cp[fc], 16, 64);
        cp[fc] += __shfl_xor(cp[fc], 32, 64);
      }
      if (l < 16) {
        int off = (cb - cs0) + l;
#pragma unroll
        for (int fc = 0; fc < 4; ++fc)
          atomicAdd(&colacc[off + fc * 16], cp[fc]);
      }
    }
    buf ^= 1;
  }

  // ---- row sums: reduce 16 col-lanes; 4 lanes atomic per wave ----
#pragma unroll
  for (int fr = 0; fr < 2; ++fr)
#pragma unroll
    for (int r = 0; r < 4; ++r) {
      float v = rowsum[fr][r];
      v += __shfl_xor(v, 1, 64);
      v += __shfl_xor(v, 2, 64);
      v += __shfl_xor(v, 4, 64);
      v += __shfl_xor(v, 8, 64);
      if ((l & 15) == 0) atomicAdd(&denom[r0 + fr * 16 + r], v);
    }

  // ---- col sums: flush colacc, one atomic per column ----
  __syncthreads();
  if (docol && tid < 256) {
    float v = colacc[tid];
    if (v != 0.f) atomicAdd(&denom[cs0 + tid], v);
  }
}

// Kernel F: + (1/N) * sum_i (log(denom_i) - pos_{i mod B} * ln2)   [pos in log2 units]
__global__ __launch_bounds__(256) void kfin(const float* __restrict__ denom,
                                            const float* __restrict__ pos,
                                            float* __restrict__ out) {
  int i = blockIdx.x * 256 + threadIdx.x;
  float v = (logf(denom[i]) - pos[i & 4095] * LN2) * (1.0f / 8192.0f);
#pragma unroll
  for (int m = 1; m < 64; m <<= 1) v += __shfl_xor(v, m, 64);
  __shared__ float part[4];
  if ((threadIdx.x & 63) == 0) part[threadIdx.x >> 6] = v;
  __syncthreads();
  if (threadIdx.x == 0)
    atomicAdd(out, part[0] + part[1] + part[2] + part[3]);
}

extern "C" void kernel_launch(void* const* d_in, const int* in_sizes, int n_in,
                              void* d_out, int out_size, void* d_ws, size_t ws_size,
                              hipStream_t stream) {
  (void)in_sizes; (void)n_in; (void)out_size; (void)ws_size;
  const float* zi = (const float*)d_in[0];
  const float* zj = (const float*)d_in[1];
  float* out = (float*)d_out;
  char* ws = (char*)d_ws;
  int* reps    = (int*)ws;                                    // 2 MB (i8 packed)
  float* denom = (float*)(ws + 2097152);                      // 32 KB
  float* pos   = (float*)(ws + 2097152 + 32768);              // 16 KB

  knorm<<<2048, 256, 0, stream>>>(zi, zj, reps, denom, out);
  ksim<<<NBLK, 512, 0, stream>>>(reps, denom, pos);
  kfin<<<32, 256, 0, stream>>>(denom, pos, out);
}

// Round 14
// 42.220 us; speedup vs baseline: 1.5485x; 1.3872x over previous
//
#include <hip/hip_runtime.h>
#include <hip/hip_bf16.h>
#include <stdint.h>

#define NROWS 8192
#define BROWS 4096
#define LN2 0.6931471805599453f
#define FSC 8.944507e-4f        // (1/T)*log2(e) / 127^2, T=0.1
#define NBLK 1056               // sum_{it=0}^{63} ceil((8192-128it)/256) = 8*132

typedef __attribute__((ext_vector_type(4))) int i32x4;

__device__ inline void gload_lds16(const void* g, void* l) {
  __builtin_amdgcn_global_load_lds((const __attribute__((address_space(1))) void*)g,
                                   (__attribute__((address_space(3))) void*)l,
                                   16, 0, 0);
}

// Kernel A: L2-normalize rows, quantize to i8 (q = rn(127*v/||v||)); zero denom/out.
__global__ __launch_bounds__(256) void knorm(const float* __restrict__ zi,
                                             const float* __restrict__ zj,
                                             int* __restrict__ reps,   // i8 packed, 64 ints/row
                                             float* __restrict__ denom,
                                             float* __restrict__ out) {
  int w = threadIdx.x >> 6, l = threadIdx.x & 63;
  int row = blockIdx.x * 4 + w;
  const float* src = (row < BROWS) ? (zi + (size_t)row * 256)
                                   : (zj + (size_t)(row - BROWS) * 256);
  float4 v = ((const float4*)src)[l];
  float ss = v.x * v.x + v.y * v.y + v.z * v.z + v.w * v.w;
#pragma unroll
  for (int m = 1; m < 64; m <<= 1) ss += __shfl_xor(ss, m, 64);
  float sc = 127.0f / fmaxf(sqrtf(ss), 1e-12f);
  int q0 = __float2int_rn(v.x * sc), q1 = __float2int_rn(v.y * sc);
  int q2 = __float2int_rn(v.z * sc), q3 = __float2int_rn(v.w * sc);
  reps[(size_t)row * 64 + l] =
      (q0 & 255) | ((q1 & 255) << 8) | ((q2 & 255) << 16) | ((q3 & 255) << 24);
  if (l == 0) denom[row] = 0.f;
  if (row == 0 && l == 0) out[0] = 0.f;
}

// Kernel B: upper-tri sim, i8 MFMA 16x16x64. R11's exact per-wave core and
// schedule; grid recut to 128-row strip x 256-col chunk -> 1056 blocks so
// 4 blocks/CU (16 waves) are truly resident.
__global__ __launch_bounds__(256, 4) void ksim(const int* __restrict__ reps_,
                                               float* __restrict__ denom,
                                               float* __restrict__ pos) {
  __shared__ uint4 smem[2][1024];    // 2 x 64 reps-rows x 256 B = 32 KB
  __shared__ float colacc[256];      // 1 KB
  int tid = threadIdx.x, w = tid >> 6, l = tid & 63;
  int kgrp = l >> 4;

  // ---- XCD swizzle (1056 = 8*132, bijective) + block -> (strip it, chunk q) ----
  int b = blockIdx.x;
  int orig = (b & 7) * 132 + (b >> 3);
  int rem = orig, it = 0, ch;
  while (rem >= (ch = (NROWS - 128 * it + 255) >> 8)) { rem -= ch; ++it; }
  int q = rem;
  int rowbase = it * 128;
  int cs0 = rowbase + q * 256;
  int len = NROWS - cs0; if (len > 256) len = 256;
  int ntile = len >> 6;              // 4, or 2 for the last chunk of odd strips

  colacc[tid] = 0.f;

  // ---- staging: 64 reps-rows x 256B -> 16KB buffer; linear dest, swizzled src.
  //      16 chunks of 1KB (4 rows each); 4 waves x 4 chunks ----
  auto stage = [&](int bufi, int colbase) {
#pragma unroll
    for (int i = 0; i < 4; ++i) {
      int c2 = w * 4 + i;
      int lr = c2 * 4 + (l >> 4);    // local row 0..63
      int kb = ((l & 15) * 16) ^ ((lr & 3) << 4);
      gload_lds16((const char*)reps_ + (size_t)(colbase + lr) * 256 + kb,
                  (void*)&smem[bufi][c2 * 64]);
    }
  };
  stage(0, cs0);

  // ---- A fragments: wave w owns rows rowbase+32w..+32; lane holds row
  //      +fr*16+(l&15), bytes [kk*64 + kgrp*16, +16) ----
  i32x4 a[2][4];
  {
    const uint4* r4 = (const uint4*)reps_;
    int arow = rowbase + w * 32 + (l & 15);
#pragma unroll
    for (int fr = 0; fr < 2; ++fr)
#pragma unroll
      for (int kk = 0; kk < 4; ++kk)
        a[fr][kk] = __builtin_bit_cast(i32x4,
            r4[(size_t)(arow + fr * 16) * 16 + kk * 4 + kgrp]);
  }

  // ---- per-kk LDS byte offsets for fc=0 (row = l&15); fc adds +16*256 ----
  int lds_a[4];
  {
    int r0l = l & 15;
    int swz = (r0l & 3) << 4;
#pragma unroll
    for (int kk = 0; kk < 4; ++kk)
      lds_a[kk] = r0l * 256 + ((kk * 64 + kgrp * 16) ^ swz);
  }

  float rowsum[2][4];
#pragma unroll
  for (int fr = 0; fr < 2; ++fr)
#pragma unroll
    for (int r = 0; r < 4; ++r) rowsum[fr][r] = 0.f;

  int r0 = rowbase + w * 32 + kgrp * 4;
  int buf = 0;
  bool posChunk = (q == 16) && (it < 32);

  for (int t = 0; t < ntile; ++t) {
    asm volatile("s_waitcnt vmcnt(0)" ::: "memory");   // own stage(t) loads landed
    __builtin_amdgcn_sched_barrier(0);
    __builtin_amdgcn_s_barrier();      // all waves' stage(t) landed; buf^1 free
    __builtin_amdgcn_sched_barrier(0);
    if (t + 1 < ntile) stage(buf ^ 1, cs0 + 64 * (t + 1));

    const char* bb = (const char*)&smem[0][0] + buf * 16384;
    i32x4 acc[2][4];
    const i32x4 zero = {0, 0, 0, 0};
    __builtin_amdgcn_s_setprio(1);
#pragma unroll
    for (int kk = 0; kk < 4; ++kk) {
      i32x4 bf[4];
#pragma unroll
      for (int fc = 0; fc < 4; ++fc)
        bf[fc] = *(const i32x4*)(bb + lds_a[kk] + fc * 4096);
#pragma unroll
      for (int fr = 0; fr < 2; ++fr)
#pragma unroll
        for (int fc = 0; fc < 4; ++fc) {
          if (kk == 0)
            acc[fr][fc] = __builtin_amdgcn_mfma_i32_16x16x64_i8(a[fr][0], bf[fc], zero, 0, 0, 0);
          else
            acc[fr][fc] = __builtin_amdgcn_mfma_i32_16x16x64_i8(a[fr][kk], bf[fc], acc[fr][fc], 0, 0, 0);
        }
    }
    __builtin_amdgcn_s_setprio(0);

    // ---- epilogue: s = I*FSC; e = exp2(s); diag mask; rowsum + col partials ----
    int cb = cs0 + 64 * t;
    bool docol = !(q == 0 && t < 2);        // diag 128-col window: rowsum only
    bool dopos = posChunk && (t < 2);
    float cp[4] = {0.f, 0.f, 0.f, 0.f};
    int cbase = cb + (l & 15);
#pragma unroll
    for (int fr = 0; fr < 2; ++fr)
#pragma unroll
      for (int fc = 0; fc < 4; ++fc)
#pragma unroll
        for (int r = 0; r < 4; ++r) {
          int rg = r0 + fr * 16 + r;
          int cg = cbase + fc * 16;
          float s = (float)acc[fr][fc][r] * FSC;
          float e = __builtin_amdgcn_exp2f(s);
          e = (rg == cg) ? 0.f : e;
          if (dopos && cg == rg + BROWS) pos[rg] = s;
          rowsum[fr][r] += e;
          cp[fc] += e;
        }
    if (docol) {
#pragma unroll
      for (int fc = 0; fc < 4; ++fc) {
        cp[fc] += __shfl_xor(cp[fc], 16, 64);
        cp[fc] += __shfl_xor(cp[fc], 32, 64);
      }
      if (l < 16) {
        int off = (cb - cs0) + l;
#pragma unroll
        for (int fc = 0; fc < 4; ++fc)
          atomicAdd(&colacc[off + fc * 16], cp[fc]);
      }
    }
    buf ^= 1;
  }

  // ---- row sums: reduce 16 col-lanes; 4 lanes atomic per wave ----
#pragma unroll
  for (int fr = 0; fr < 2; ++fr)
#pragma unroll
    for (int r = 0; r < 4; ++r) {
      float v = rowsum[fr][r];
      v += __shfl_xor(v, 1, 64);
      v += __shfl_xor(v, 2, 64);
      v += __shfl_xor(v, 4, 64);
      v += __shfl_xor(v, 8, 64);
      if ((l & 15) == 0) atomicAdd(&denom[r0 + fr * 16 + r], v);
    }

  // ---- col sums: flush colacc, one atomic per column ----
  __syncthreads();
  {
    float v = colacc[tid];
    int col = cs0 + tid;
    if (col < NROWS && v != 0.f) atomicAdd(&denom[col], v);
  }
}

// Kernel F: + (1/N) * sum_i (log(denom_i) - pos_{i mod B} * ln2)   [pos in log2 units]
__global__ __launch_bounds__(256) void kfin(const float* __restrict__ denom,
                                            const float* __restrict__ pos,
                                            float* __restrict__ out) {
  int i = blockIdx.x * 256 + threadIdx.x;
  float v = (logf(denom[i]) - pos[i & 4095] * LN2) * (1.0f / 8192.0f);
#pragma unroll
  for (int m = 1; m < 64; m <<= 1) v += __shfl_xor(v, m, 64);
  __shared__ float part[4];
  if ((threadIdx.x & 63) == 0) part[threadIdx.x >> 6] = v;
  __syncthreads();
  if (threadIdx.x == 0)
    atomicAdd(out, part[0] + part[1] + part[2] + part[3]);
}

extern "C" void kernel_launch(void* const* d_in, const int* in_sizes, int n_in,
                              void* d_out, int out_size, void* d_ws, size_t ws_size,
                              hipStream_t stream) {
  (void)in_sizes; (void)n_in; (void)out_size; (void)ws_size;
  const float* zi = (const float*)d_in[0];
  const float* zj = (const float*)d_in[1];
  float* out = (float*)d_out;
  char* ws = (char*)d_ws;
  int* reps    = (int*)ws;                                    // 2 MB (i8 packed)
  float* denom = (float*)(ws + 2097152);                      // 32 KB
  float* pos   = (float*)(ws + 2097152 + 32768);              // 16 KB

  knorm<<<2048, 256, 0, stream>>>(zi, zj, reps, denom, out);
  ksim<<<NBLK, 256, 0, stream>>>(reps, denom, pos);
  kfin<<<32, 256, 0, stream>>>(denom, pos, out);
}